// Round 1
// baseline (10695.418 us; speedup 1.0000x reference)
//
#include <hip/hip_runtime.h>
#include <hip/hip_bf16.h>
#include <stdint.h>

#define AS1 __attribute__((address_space(1)))
#define AS3 __attribute__((address_space(3)))

typedef float f32x4 __attribute__((ext_vector_type(4)));
typedef short short8 __attribute__((ext_vector_type(8)));

__device__ __forceinline__ unsigned short f2bf(float f) {
  union { float f; unsigned int u; } v; v.f = f;
  unsigned int r = v.u + 0x7FFFu + ((v.u >> 16) & 1u);   // RNE
  return (unsigned short)(r >> 16);
}

__device__ __forceinline__ void gload_lds16(const void* g, void* l) {
  __builtin_amdgcn_global_load_lds((const AS1 unsigned int*)g,
                                   (AS3 unsigned int*)l, 16, 0, 0);
}

// ---------------------------------------------------------------------------
// prep: bias1 = b_i2h + b_h2h (1024), zero the 512 barrier flags
// ---------------------------------------------------------------------------
__global__ void prep_kernel(const float* __restrict__ a, const float* __restrict__ b,
                            float* __restrict__ o, unsigned int* __restrict__ flags) {
  int i = blockIdx.x * 256 + threadIdx.x;   // grid 4x256 == 1024
  o[i] = a[i] + b[i];
  if (i < 512) flags[i] = 0u;
}

// ---------------------------------------------------------------------------
// W [K][N] fp32 -> Wt [N][K] bf16   (64x64 tiles)
// ---------------------------------------------------------------------------
__global__ __launch_bounds__(256)
void w_transpose_bf16(const float* __restrict__ W, unsigned short* __restrict__ Wt, int dim) {
  __shared__ float tile[64][65];
  const int bk = blockIdx.x, bn = blockIdx.y;
  const int tid = threadIdx.x;
  const int c = tid & 63, r0 = tid >> 6;
  #pragma unroll
  for (int i = 0; i < 16; i++) {
    int r = i * 4 + r0;
    tile[r][c] = W[(size_t)(bk * 64 + r) * dim + bn * 64 + c];
  }
  __syncthreads();
  #pragma unroll
  for (int i = 0; i < 16; i++) {
    int r = i * 4 + r0;
    Wt[(size_t)(bn * 64 + r) * dim + bk * 64 + c] = f2bf(tile[c][r]);
  }
}

// ---------------------------------------------------------------------------
// C[M][N] = A[M][K](fp32, cvt->bf16 in-kernel) @ Bt[N][K](bf16)^T + bias[N]
// m97 structure: BM=BN=128, BK=32, 4 waves, global_load_lds width 16.
// ---------------------------------------------------------------------------
__global__ __launch_bounds__(256)
void gemm128(const float* __restrict__ A, const unsigned short* __restrict__ Bt,
             const float* __restrict__ bias, float* __restrict__ C,
             int M, int N, int K) {
  const int bm = blockIdx.x, bn = blockIdx.y;
  const int tid = threadIdx.x;
  const int wave = tid >> 6, lane = tid & 63;
  const int wm = (wave >> 1) * 64, wn = (wave & 1) * 64;
  const int fr = lane & 15, fq = lane >> 4;

  __shared__ float AsF[128 * 32];          // 16 KB
  __shared__ unsigned short Bs[128 * 32];  // 8 KB

  f32x4 acc[4][4] = {};

  const size_t arow0 = (size_t)bm * 128;
  const size_t brow0 = (size_t)bn * 128;

  for (int kt = 0; kt < K; kt += 32) {
    #pragma unroll
    for (int i = 0; i < 4; i++) {                     // A: 128x32 f32, 16B/lane
      int idx = i * 256 + tid;
      int r = idx >> 3, c = (idx & 7) * 4;
      gload_lds16(A + (arow0 + r) * (size_t)K + kt + c, &AsF[idx * 4]);
    }
    #pragma unroll
    for (int i = 0; i < 2; i++) {                     // B: 128x32 bf16
      int idx = i * 256 + tid;
      int r = idx >> 2, c = (idx & 3) * 8;
      gload_lds16(Bt + (brow0 + r) * (size_t)K + kt + c, &Bs[idx * 8]);
    }
    __syncthreads();

    short8 af[4], bf[4];
    #pragma unroll
    for (int i = 0; i < 4; i++) {
      const float* pa = &AsF[(wm + i * 16 + fr) * 32 + fq * 8];
      #pragma unroll
      for (int q = 0; q < 8; q++) af[i][q] = (short)f2bf(pa[q]);
      bf[i] = *(const short8*)&Bs[(wn + i * 16 + fr) * 32 + fq * 8];
    }
    #pragma unroll
    for (int i = 0; i < 4; i++)
      #pragma unroll
      for (int j = 0; j < 4; j++)
        acc[i][j] = __builtin_amdgcn_mfma_f32_16x16x32_bf16(af[i], bf[j], acc[i][j], 0, 0, 0);
    __syncthreads();
  }

  #pragma unroll
  for (int i = 0; i < 4; i++) {
    int row = bm * 128 + wm + i * 16 + fq * 4;
    #pragma unroll
    for (int j = 0; j < 4; j++) {
      int col = bn * 128 + wn + j * 16 + fr;
      float bb = bias[col];
      #pragma unroll
      for (int r = 0; r < 4; r++)
        C[(size_t)(row + r) * N + col] = acc[i][j][r] + bb;
    }
  }
}

// ---------------------------------------------------------------------------
// Recurrence: 64 blocks, block jb owns output cols [16*jb, 16*jb+16).
// W-slice (16 cols x 1024 k, bf16) pinned in LDS, XOR-swizzled.
// h exchanged via ping-pong bf16 buffer + per-step 64-block barrier.
// HX = d_out hidden half: x_proj in, h_t out (same addresses, same block).
// ---------------------------------------------------------------------------
__global__ __launch_bounds__(256, 1)
void rnn_scan(float* __restrict__ HX,                   // [64][512][1024] fp32
              const unsigned short* __restrict__ WtH,   // [1024][1024] bf16 [n][k]
              unsigned short* __restrict__ Hbuf,        // 2 x [64][1024] bf16
              unsigned int* __restrict__ flags) {       // [512]
  const int jb = blockIdx.x;
  const int tid = threadIdx.x;
  const int wave = tid >> 6, lane = tid & 63;
  const int fr = lane & 15, fq = lane >> 4;
  const int col = jb * 16 + fr;          // output / B-frag column
  const int brow = wave * 16 + fr;       // A-frag batch row

  __shared__ unsigned short Wl[16 * 1024];   // 32 KB

  // stage W slice into LDS with XOR swizzle (byte ^= (c&7)<<4 within row)
  #pragma unroll
  for (int i = 0; i < 8; i++) {
    int idx = i * 256 + tid;
    int c = idx >> 7, kk = (idx & 127) * 8;
    short8 v = *(const short8*)(WtH + (size_t)(jb * 16 + c) * 1024 + kk);
    int byteoff = c * 2048 + ((kk * 2) ^ ((c & 7) << 4));
    *(short8*)((char*)Wl + byteoff) = v;
  }
  __syncthreads();

  const char* wrow = (const char*)Wl + fr * 2048;
  const int wswz = (fr & 7) << 4;

  for (int t = 0; t < 512; t++) {
    // xp for this thread's 4 outputs (rows b = wave*16 + fq*4 + r)
    float xp[4];
    #pragma unroll
    for (int r = 0; r < 4; r++) {
      int b = wave * 16 + fq * 4 + r;
      xp[r] = HX[((size_t)b * 512 + t) * 1024 + col];
    }

    f32x4 ac[4] = {};
    if (t > 0) {
      const unsigned short* hrow =
          Hbuf + (size_t)((t - 1) & 1) * 64 * 1024 + (size_t)brow * 1024;
      short8 a[32];
      #pragma unroll
      for (int ks = 0; ks < 32; ks++)           // issue all 32 A loads up front
        a[ks] = *(const short8*)(hrow + ks * 32 + fq * 8);
      #pragma unroll
      for (int ks = 0; ks < 32; ks++) {
        short8 bfr = *(const short8*)(wrow + ((ks * 64 + fq * 16) ^ wswz));
        ac[ks & 3] = __builtin_amdgcn_mfma_f32_16x16x32_bf16(a[ks], bfr, ac[ks & 3], 0, 0, 0);
      }
    }
    f32x4 acc = (ac[0] + ac[1]) + (ac[2] + ac[3]);

    unsigned short* hw = Hbuf + (size_t)(t & 1) * 64 * 1024;
    #pragma unroll
    for (int r = 0; r < 4; r++) {
      int b = wave * 16 + fq * 4 + r;
      float h = xp[r] + acc[r];
      h = h > 0.f ? h : 0.f;
      HX[((size_t)b * 512 + t) * 1024 + col] = h;   // fp32 hidden output
      if (t < 511) hw[b * 1024 + col] = f2bf(h);    // bf16 for next step
    }

    if (t < 511) {
      __threadfence();                 // release own h writes (agent scope)
      __syncthreads();
      if (tid == 0) {
        __hip_atomic_fetch_add(&flags[t], 1u, __ATOMIC_RELEASE, __HIP_MEMORY_SCOPE_AGENT);
        while (__hip_atomic_load(&flags[t], __ATOMIC_ACQUIRE, __HIP_MEMORY_SCOPE_AGENT) < 64u)
          __builtin_amdgcn_s_sleep(1);
      }
      __syncthreads();
      __threadfence();                 // acquire before reading peers' h
    }
  }
}

// ---------------------------------------------------------------------------
extern "C" void kernel_launch(void* const* d_in, const int* in_sizes, int n_in,
                              void* d_out, int out_size, void* d_ws, size_t ws_size,
                              hipStream_t stream) {
  (void)in_sizes; (void)n_in; (void)out_size;
  const float* seq  = (const float*)d_in[0];
  const float* Wi2h = (const float*)d_in[1];
  const float* bi2h = (const float*)d_in[2];
  const float* Wh2h = (const float*)d_in[3];
  const float* bh2h = (const float*)d_in[4];
  const float* Wout = (const float*)d_in[5];
  const float* bout = (const float*)d_in[6];

  float* hidden = (float*)d_out;                         // [64][512][1024]
  float* output = hidden + (size_t)64 * 512 * 1024;      // [64][512][1024]

  char* ws = (char*)d_ws;
  // layout: flags(2KB)@0 | bias1(4KB)@4K | WtI(2MB)@64K | WtH | WtO | Hbuf(256KB)
  const size_t needed = 65536 + 3 * (size_t)2097152 + 262144;
  if (ws_size < needed) return;
  unsigned int* flags  = (unsigned int*)ws;
  float* bias1         = (float*)(ws + 4096);
  unsigned short* WtI  = (unsigned short*)(ws + 65536);
  unsigned short* WtH  = WtI + (size_t)1024 * 1024;
  unsigned short* WtO  = WtH + (size_t)1024 * 1024;
  unsigned short* Hbuf = (unsigned short*)(ws + 65536 + 3 * (size_t)2097152);

  prep_kernel<<<4, 256, 0, stream>>>(bi2h, bh2h, bias1, flags);
  dim3 tg(16, 16);
  w_transpose_bf16<<<tg, 256, 0, stream>>>(Wi2h, WtI, 1024);
  w_transpose_bf16<<<tg, 256, 0, stream>>>(Wh2h, WtH, 1024);
  w_transpose_bf16<<<tg, 256, 0, stream>>>(Wout, WtO, 1024);

  // x_proj -> hidden half of d_out
  gemm128<<<dim3(256, 8), 256, 0, stream>>>(seq, WtI, bias1, hidden, 32768, 1024, 1024);
  // serial scan (rewrites hidden half in place with h_t)
  rnn_scan<<<64, 256, 0, stream>>>(hidden, WtH, Hbuf, flags);
  // output GEMM reads hidden fp32 back
  gemm128<<<dim3(256, 8), 256, 0, stream>>>(hidden, WtO, bout, output, 32768, 1024, 1024);
}